// Round 1
// baseline (343.606 us; speedup 1.0000x reference)
//
#include <hip/hip_runtime.h>

// Locally-connected 3D conv with flipout perturbation (MI355X / gfx950).
//
// All indices computed analytically; rows/cols inputs ignored.
// nnz layout: nnz = o*216 + ((kx*3+ky)*3+kz)*8 + ci, o = output row.
// One wave (64 lanes) per output row; 216 taps = 54 float4 per array.

constexpr int B = 4, IX = 32, IY = 32, IZ = 16, CIN = 8;
constexpr int KX = 3, KY = 3, KZ = 3, F = 8;
constexpr int OX = IX - KX + 1;   // 30
constexpr int OY = IY - KY + 1;   // 30
constexpr int OZ = IZ - KZ + 1;   // 14
constexpr int IN_SIZE  = IX * IY * IZ * CIN;  // 131072
constexpr int OUT_SIZE = OX * OY * OZ * F;    // 100800
constexpr int TAPS = KX * KY * KZ * CIN;      // 216

__global__ __launch_bounds__(256, 4) void lc3d_flipout_kernel(
    const float* __restrict__ x,        // [B, IN_SIZE]
    const float* __restrict__ kmean,    // [NNZ]
    const float* __restrict__ kstd,     // [NNZ]
    const float* __restrict__ bias,     // [OUT_SIZE]
    const float* __restrict__ eps,      // [NNZ]
    const float* __restrict__ sgn_in,   // [B, IN_SIZE]
    const float* __restrict__ sgn_out,  // [B, OUT_SIZE]
    float* __restrict__ out)            // [B, OUT_SIZE]
{
    const int gtid = blockIdx.x * blockDim.x + threadIdx.x;
    const int o    = gtid >> 6;          // one wave per output row
    const int lane = threadIdx.x & 63;
    if (o >= OUT_SIZE) return;

    // decode o = ((ox*OY + oy)*OZ + oz)*F + fo   (F==8)
    const int t  = o >> 3;
    const int oz = t % OZ;
    const int t2 = t / OZ;
    const int oy = t2 % OY;
    const int ox = t2 / OY;

    float ms0 = 0.f, ms1 = 0.f, ms2 = 0.f, ms3 = 0.f;  // mean-path sums per batch
    float ps0 = 0.f, ps1 = 0.f, ps2 = 0.f, ps3 = 0.f;  // perturbation sums per batch

    if (lane < TAPS / 4) {               // 54 active lanes, 4 taps each
        const int s   = lane >> 1;       // spatial tap 0..26
        const int ci0 = (lane & 1) << 2; // ci 0..3 or 4..7
        const int kz  = s % KZ;
        const int sy  = s / KZ;
        const int ky  = sy % KY;
        const int kx  = sy / KY;
        const int col = (((ox + kx) * IY + (oy + ky)) * IZ + (oz + kz)) * CIN + ci0;
        const int nb  = o * TAPS + (lane << 2);   // < 21.8M, fits int32; 16B aligned

        const float4 m4 = *reinterpret_cast<const float4*>(kmean + nb);
        const float4 s4 = *reinterpret_cast<const float4*>(kstd  + nb);
        const float4 e4 = *reinterpret_cast<const float4*>(eps   + nb);
        float4 se;
        se.x = s4.x * e4.x; se.y = s4.y * e4.y; se.z = s4.z * e4.z; se.w = s4.w * e4.w;

#define ACC_BATCH(bi, msv, psv)                                                     \
        {                                                                           \
            const float4 x4 = *reinterpret_cast<const float4*>(x + (bi)*IN_SIZE + col);      \
            const float4 si = *reinterpret_cast<const float4*>(sgn_in + (bi)*IN_SIZE + col); \
            msv += m4.x*x4.x + m4.y*x4.y + m4.z*x4.z + m4.w*x4.w;                   \
            psv += se.x*(x4.x*si.x) + se.y*(x4.y*si.y)                              \
                 + se.z*(x4.z*si.z) + se.w*(x4.w*si.w);                             \
        }
        ACC_BATCH(0, ms0, ps0)
        ACC_BATCH(1, ms1, ps1)
        ACC_BATCH(2, ms2, ps2)
        ACC_BATCH(3, ms3, ps3)
#undef ACC_BATCH
    }

    // 64-lane butterfly reduce of all 8 accumulators (inactive lanes hold 0)
#pragma unroll
    for (int off = 32; off >= 1; off >>= 1) {
        ms0 += __shfl_xor(ms0, off, 64);
        ms1 += __shfl_xor(ms1, off, 64);
        ms2 += __shfl_xor(ms2, off, 64);
        ms3 += __shfl_xor(ms3, off, 64);
        ps0 += __shfl_xor(ps0, off, 64);
        ps1 += __shfl_xor(ps1, off, 64);
        ps2 += __shfl_xor(ps2, off, 64);
        ps3 += __shfl_xor(ps3, off, 64);
    }

    if (lane < B) {
        // static-index selects (no runtime-indexed array -> no scratch, rule #20)
        const float m = (lane == 0) ? ms0 : (lane == 1) ? ms1 : (lane == 2) ? ms2 : ms3;
        const float p = (lane == 0) ? ps0 : (lane == 1) ? ps1 : (lane == 2) ? ps2 : ps3;
        out[lane * OUT_SIZE + o] = m + sgn_out[lane * OUT_SIZE + o] * p + bias[o];
    }
}

extern "C" void kernel_launch(void* const* d_in, const int* in_sizes, int n_in,
                              void* d_out, int out_size, void* d_ws, size_t ws_size,
                              hipStream_t stream) {
    const float* x       = (const float*)d_in[0];
    const float* kmean   = (const float*)d_in[1];
    const float* kstd    = (const float*)d_in[2];
    const float* bias    = (const float*)d_in[3];
    const float* eps     = (const float*)d_in[4];
    const float* sgn_in  = (const float*)d_in[5];
    const float* sgn_out = (const float*)d_in[6];
    // d_in[7] = rows, d_in[8] = cols : unused (indices computed analytically)
    float* out = (float*)d_out;

    const int waves   = OUT_SIZE;                 // one wave per output row
    const int threads = 256;                      // 4 waves per block
    const int blocks  = (waves * 64 + threads - 1) / threads;  // 25200

    hipLaunchKernelGGL(lc3d_flipout_kernel, dim3(blocks), dim3(threads), 0, stream,
                       x, kmean, kstd, bias, eps, sgn_in, sgn_out, out);
}